// Round 2
// 200.830 us; speedup vs baseline: 1.0134x; 1.0134x over previous
//
#include <hip/hip_runtime.h>
#include <hip/hip_bf16.h>
#include <stdint.h>
#include <stddef.h>

typedef __bf16 bf16;
typedef bf16 bf16x8 __attribute__((ext_vector_type(8)));
typedef float f32x4 __attribute__((ext_vector_type(4)));

#define EPSN 1e-8f
#define TWO_PI 6.283185307179586f

#define NB 16384   // batch
#define NH 512     // hidden
#define NI 256     // input
#define KTOT 1280  // 512 + 512 + 256
#define NKT 20     // K-tiles of 64

__device__ __forceinline__ float2 cmul(float2 a, float2 b) {
  return make_float2(a.x * b.x - a.y * b.y, a.x * b.y + a.y * b.x);
}
// a * conj(b)
__device__ __forceinline__ float2 cmulconj(float2 a, float2 b) {
  return make_float2(a.x * b.x + a.y * b.y, a.y * b.x - a.x * b.y);
}
__device__ __forceinline__ float2 cadd(float2 a, float2 b) {
  return make_float2(a.x + b.x, a.y + b.y);
}
__device__ __forceinline__ int brev9(int i) {
  return (int)(__brev((unsigned)i) >> 23);
}

// async global->LDS, 16B per lane; lds dest = wave-uniform base + lane*16
__device__ __forceinline__ void gload16(const bf16* g, bf16* l) {
  __builtin_amdgcn_global_load_lds(
      (const __attribute__((address_space(1))) void*)g,
      (__attribute__((address_space(3))) void*)l, 16, 0, 0);
}

// ---------------------------------------------------------------------------
// prep: unchanged from the verified 200µs kernel.
// blocks [0,512) = build_U column j; blocks [512, 10752) = pack_A octets.
// ---------------------------------------------------------------------------
__global__ __launch_bounds__(256) void prep(
    const float* __restrict__ ang, const float* __restrict__ rre,
    const float* __restrict__ rim, const float* __restrict__ wre,
    const float* __restrict__ wim, const int* __restrict__ perm,
    const float* __restrict__ hxre, const float* __restrict__ hxim,
    const float* __restrict__ x, bf16* __restrict__ Bm,
    bf16* __restrict__ Apack) {
  __shared__ float2 bufA[512];
  __shared__ float2 bufB[512];
  __shared__ float2 redw[4];
  __shared__ float2 bc;
  __shared__ float2 red2[256];

  const int bid = blockIdx.x;
  const int t = threadIdx.x;

  if (bid >= 512) {
    // ---------------- pack_A ----------------
    const int tid = (bid - 512) * 256 + t;  // 0 .. 16384*160-1
    const int b = tid / 160;
    const int o = tid - b * 160;
    const float* src;
    if (o < 64)
      src = hxre + (size_t)b * 512 + o * 8;
    else if (o < 128)
      src = hxim + (size_t)b * 512 + (o - 64) * 8;
    else
      src = x + (size_t)b * 256 + (o - 128) * 8;
    float4 f0 = ((const float4*)src)[0];
    float4 f1 = ((const float4*)src)[1];
    bf16x8 v;
    v[0] = (bf16)f0.x; v[1] = (bf16)f0.y; v[2] = (bf16)f0.z; v[3] = (bf16)f0.w;
    v[4] = (bf16)f1.x; v[5] = (bf16)f1.y; v[6] = (bf16)f1.z; v[7] = (bf16)f1.w;
    *(bf16x8*)(Apack + (size_t)b * KTOT + o * 8) = v;
    return;
  }

  // ---------------- build_U for column j = bid ----------------
  const int j = bid;
  const int j0 = t, j1 = t + 256;

  const float r1x0 = rre[j0], r1y0 = rim[j0];
  const float r1x1 = rre[j1], r1y1 = rim[j1];
  const float r2x0 = rre[512 + j0], r2y0 = rim[512 + j0];
  const float r2x1 = rre[512 + j1], r2y1 = rim[512 + j1];
  red2[t] = make_float2(r1x0 * r1x0 + r1y0 * r1y0 + r1x1 * r1x1 + r1y1 * r1y1,
                        r2x0 * r2x0 + r2y0 * r2y0 + r2x1 * r2x1 + r2y1 * r2y1);
  __syncthreads();
  for (int off = 128; off > 0; off >>= 1) {
    if (t < off) {
      red2[t].x += red2[t + off].x;
      red2[t].y += red2[t + off].y;
    }
    __syncthreads();
  }
  const float inv1 = 1.0f / (sqrtf(red2[0].x) + EPSN);
  const float inv2 = 1.0f / (sqrtf(red2[0].y) + EPSN);
  const float2 v1a = make_float2(r1x0 * inv1, r1y0 * inv1);
  const float2 v1b = make_float2(r1x1 * inv1, r1y1 * inv1);
  const float2 v2a = make_float2(r2x0 * inv2, r2y0 * inv2);
  const float2 v2b = make_float2(r2x1 * inv2, r2y1 * inv2);

  {
    float sj, cj;
    __sincosf(ang[j], &sj, &cj);
    const float2 dj = make_float2(cj, sj);
    float2 z = make_float2(0.f, 0.f);
    bufA[brev9(j0)] = (j0 == j) ? dj : z;
    bufA[brev9(j1)] = (j1 == j) ? dj : z;
  }
  __syncthreads();

#pragma unroll
  for (int st = 0; st < 9; ++st) {
    const int half = 1 << st;
    const int pos = t & (half - 1);
    const int i0 = ((t >> st) << (st + 1)) + pos;
    const int i1 = i0 + half;
    const float angv = -TWO_PI * (float)pos / (float)(2 << st);
    float sn, cs;
    __sincosf(angv, &sn, &cs);
    float2 u = bufA[i0];
    float2 w = bufA[i1];
    float2 tw = make_float2(cs * w.x - sn * w.y, cs * w.y + sn * w.x);
    bufA[i0] = make_float2(u.x + tw.x, u.y + tw.y);
    bufA[i1] = make_float2(u.x - tw.x, u.y - tw.y);
    __syncthreads();
  }

  {
    float2 p = cadd(cmul(bufA[j0], v1a), cmul(bufA[j1], v1b));
    for (int off = 32; off > 0; off >>= 1) {
      p.x += __shfl_down(p.x, off);
      p.y += __shfl_down(p.y, off);
    }
    if ((t & 63) == 0) redw[t >> 6] = p;
    __syncthreads();
    if (t == 0) bc = cadd(cadd(redw[0], redw[1]), cadd(redw[2], redw[3]));
    __syncthreads();
  }
  const float2 dot1 = bc;

  {
    float2 c0 = cmulconj(dot1, v1a);
    float2 c1 = cmulconj(dot1, v1b);
    float2 a0 = bufA[j0], a1 = bufA[j1];
    bufA[j0] = make_float2(a0.x - 2.f * c0.x, a0.y - 2.f * c0.y);
    bufA[j1] = make_float2(a1.x - 2.f * c1.x, a1.y - 2.f * c1.y);
  }
  __syncthreads();

  {
    int p0 = perm[j0], p1 = perm[j1];
    float s0, c0, s1, c1;
    __sincosf(ang[512 + j0], &s0, &c0);
    __sincosf(ang[512 + j1], &s1, &c1);
    float2 g0 = cmul(make_float2(c0, s0), bufA[p0]);
    float2 g1 = cmul(make_float2(c1, s1), bufA[p1]);
    bufB[brev9(j0)] = g0;
    bufB[brev9(j1)] = g1;
  }
  __syncthreads();

#pragma unroll
  for (int st = 0; st < 9; ++st) {
    const int half = 1 << st;
    const int pos = t & (half - 1);
    const int i0 = ((t >> st) << (st + 1)) + pos;
    const int i1 = i0 + half;
    const float angv = TWO_PI * (float)pos / (float)(2 << st);
    float sn, cs;
    __sincosf(angv, &sn, &cs);
    float2 u = bufB[i0];
    float2 w = bufB[i1];
    float2 tw = make_float2(cs * w.x - sn * w.y, cs * w.y + sn * w.x);
    bufB[i0] = make_float2(u.x + tw.x, u.y + tw.y);
    bufB[i1] = make_float2(u.x - tw.x, u.y - tw.y);
    __syncthreads();
  }

  {
    float2 q = cadd(cmul(bufB[j0], v2a), cmul(bufB[j1], v2b));
    for (int off = 32; off > 0; off >>= 1) {
      q.x += __shfl_down(q.x, off);
      q.y += __shfl_down(q.y, off);
    }
    if ((t & 63) == 0) redw[t >> 6] = q;
    __syncthreads();
    if (t == 0) bc = cadd(cadd(redw[0], redw[1]), cadd(redw[2], redw[3]));
    __syncthreads();
  }
  const float invN = 1.0f / 512.0f;
  const float2 dot2 = make_float2(bc.x * invN, bc.y * invN);

#pragma unroll
  for (int e = 0; e < 2; ++e) {
    const int i = (e == 0) ? j0 : j1;
    const float2 vj = (e == 0) ? v2a : v2b;
    float2 h2 = make_float2(bufB[i].x * invN, bufB[i].y * invN);
    float2 c2 = cmulconj(dot2, vj);
    float2 hh = make_float2(h2.x - 2.f * c2.x, h2.y - 2.f * c2.y);
    float s3, c3;
    __sincosf(ang[1024 + i], &s3, &c3);
    float2 u = cmul(make_float2(c3, s3), hh);  // U[i][j]
    bf16* r0 = Bm + (size_t)(2 * i) * KTOT;
    bf16* r1 = Bm + (size_t)(2 * i + 1) * KTOT;
    r0[j] = (bf16)u.x;
    r0[512 + j] = (bf16)(-u.y);
    r1[j] = (bf16)u.y;
    r1[512 + j] = (bf16)u.x;
  }

  Bm[(size_t)(2 * j) * KTOT + 1024 + t] = (bf16)wre[j * NI + t];
  Bm[(size_t)(2 * j + 1) * KTOT + 1024 + t] = (bf16)wim[j * NI + t];
}

// ---------------------------------------------------------------------------
// Fused GEMM + ModReLU, 8-phase counted-vmcnt schedule (T2+T3+T4+T5).
// M=16384, N=1024, K=1280. Tile 256x256, BK=64, 512 thr = 8 waves (2M x 4N),
// per-wave 128x64 output = acc[8][4] f32x4 (128 VGPR). LDS = 2 K-tile
// double-buffer x (A 256x64 + B 256x64) bf16 = 128 KiB -> 1 block/CU,
// grid 256 = one full-capacity round.
//
// Per K-tile: 4 C-quadrant phases (m-half x n-half), 16 MFMA each, setprio-
// wrapped. ds_reads: ph1 A(m0)+B(n0)=12, ph2 B(n1)=4, ph3 A(m1)=8, ph4 0
// (B frags held in regs across the tile). Stage units are INTERLEAVED row
// sets so each LDS region dies one phase after its single ds_read:
//   Am0 = rows {0-63,128-191}, Am1 = {64-127,192-255}        (read ph1 / ph3)
//   Bn0 = rows {q*64+0-31}, Bn1 = {q*64+32-63}, q=0..3       (read ph1 / ph2)
// Stage plan per iter (tiles T=2i buf0, T+1 buf1; 1 unit = 2 gload_lds):
//   ph1 Am1(T+1)->b1  ph2 Bn1(T+1)->b1  ph3 Am0(T+2)->b0  ph4 Bn0(T+2)->b0
//   ph5 Am1(T+2)->b0  ph6 Bn1(T+2)->b0  ph7 Am0(T+3)->b1  ph8 Bn0(T+3)->b1
// Every stage issues >=1 full barrier after the region's last read (safe),
// and vmcnt(4) at ph4/ph8 (the only waits) proves the next tile landed
// (outstanding = exactly the 2 units just issued). Never vmcnt(0) in-loop.
// Tail: prefetch tile index clamped to 19 -> benign same-data re-stages of
// dead regions. Swizzle: LDS chunk p of row r holds logical chunk p^(r&7);
// staging pre-swizzles the GLOBAL chunk ((lane&7)^(lane>>3)); reads use
// ((kh*4+lq)^(row&7)) -- identical to the verified 0-conflict kernel.
// ---------------------------------------------------------------------------

#define BARM() __builtin_amdgcn_s_barrier()
#define WVM(n) asm volatile("s_waitcnt vmcnt(" #n ")" ::: "memory")

// stage unit Am(h) of K-tile kt into A-buffer Asb (rows h*64+wv*8 and +128)
__device__ __forceinline__ void stA(const bf16* gA, bf16* Asb, int wv, int h,
                                    int kt) {
  const int r0 = h * 64 + wv * 8;
  const int r1 = r0 + 128;
  gload16(gA + (size_t)r0 * KTOT + kt * 64, Asb + r0 * 64);
  gload16(gA + (size_t)r1 * KTOT + kt * 64, Asb + r1 * 64);
}
// stage unit Bn(h): rows (u>>2)*64 + h*32 + (u&3)*8, u = wv*2+g
__device__ __forceinline__ void stB(const bf16* gB, bf16* Bsb, int wv, int h,
                                    int kt) {
  const int u0 = wv * 2, u1 = u0 + 1;
  const int r0 = (u0 >> 2) * 64 + h * 32 + (u0 & 3) * 8;
  const int r1 = (u1 >> 2) * 64 + h * 32 + (u1 & 3) * 8;
  gload16(gB + (size_t)r0 * KTOT + kt * 64, Bsb + r0 * 64);
  gload16(gB + (size_t)r1 * KTOT + kt * 64, Bsb + r1 * 64);
}

__device__ __forceinline__ void lda(const bf16* Asb, int rowbase,
                                    const int (&co)[2], bf16x8 (&af)[4][2]) {
#pragma unroll
  for (int mi = 0; mi < 4; ++mi)
#pragma unroll
    for (int kh = 0; kh < 2; ++kh)
      af[mi][kh] = *(const bf16x8*)&Asb[(rowbase + mi * 16) * 64 + co[kh]];
}
__device__ __forceinline__ void ldb(const bf16* Bsb, int rowbase,
                                    const int (&co)[2], bf16x8 (&bb)[2][2]) {
#pragma unroll
  for (int ni = 0; ni < 2; ++ni)
#pragma unroll
    for (int kh = 0; kh < 2; ++kh)
      bb[ni][kh] = *(const bf16x8*)&Bsb[(rowbase + ni * 16) * 64 + co[kh]];
}
__device__ __forceinline__ void mmq(const bf16x8 (&af)[4][2],
                                    const bf16x8 (&bb)[2][2],
                                    f32x4 (&acc)[8][4], int mh, int nh) {
  __builtin_amdgcn_s_setprio(1);
#pragma unroll
  for (int mi = 0; mi < 4; ++mi)
#pragma unroll
    for (int ni = 0; ni < 2; ++ni)
#pragma unroll
      for (int kh = 0; kh < 2; ++kh)
        acc[mh * 4 + mi][nh * 2 + ni] = __builtin_amdgcn_mfma_f32_16x16x32_bf16(
            af[mi][kh], bb[ni][kh], acc[mh * 4 + mi][nh * 2 + ni], 0, 0, 0);
  __builtin_amdgcn_s_setprio(0);
}

__global__ __launch_bounds__(512, 2) void gemm_fused(
    const bf16* __restrict__ Apack, const bf16* __restrict__ Bm,
    const float* __restrict__ beta, float* __restrict__ out) {
  __shared__ bf16 As[2][256 * 64];
  __shared__ bf16 Bs[2][256 * 64];

  const int t = threadIdx.x;
  const int lane = t & 63;
  const int wv = t >> 6;  // 0..7

  const int id = blockIdx.x;  // 0..255
  const int xcd = id & 7;
  const int lix = id >> 3;  // 0..31
  const int mBase = (xcd * 8 + (lix >> 2)) * 256;  // 64 M-panels
  const int nBase = (lix & 3) * 256;               // 4 N-panels

  // staging source: per-lane row = +(lane>>3), pre-swizzled chunk
  const int sub = lane >> 3;
  const int chunk = (lane & 7) ^ sub;
  const bf16* gA = Apack + (size_t)(mBase + sub) * KTOT + chunk * 8;
  const bf16* gB = Bm + (size_t)(nBase + sub) * KTOT + chunk * 8;

  const int lr = lane & 15;
  const int lq = lane >> 4;
  const int lrm = lr & 7;
  const int waveM = wv & 1;   // 2 M positions x 128 rows
  const int waveN = wv >> 1;  // 4 N positions x 64 cols

  const int co[2] = {(lq ^ lrm) * 8, ((4 + lq) ^ lrm) * 8};
  const int arow = waveM * 128 + lr;
  const int brow = waveN * 64 + lr;

  f32x4 acc[8][4] = {};
  bf16x8 af[4][2], b0[2][2], b1[2][2];

  // ---- prologue: tile0 (4 units -> buf0), tile1 Am0/Bn0 (-> buf1) ----
  stA(gA, &As[0][0], wv, 0, 0);
  stB(gB, &Bs[0][0], wv, 0, 0);
  stA(gA, &As[0][0], wv, 1, 0);
  stB(gB, &Bs[0][0], wv, 1, 0);
  stA(gA, &As[1][0], wv, 0, 1);
  stB(gB, &Bs[1][0], wv, 0, 1);
  WVM(4);  // tile 0 landed; tile 1's first 2 units in flight
  BARM();

  for (int i = 0; i < 10; ++i) {
    const int t1 = 2 * i + 1;
    const int t2 = (t1 + 1 < NKT) ? t1 + 1 : NKT - 1;
    const int t3 = (t1 + 2 < NKT) ? t1 + 2 : NKT - 1;

    // ================= tile 2i from buf0 =================
    // ph1 (m0,n0)
    lda(&As[0][0], arow, co, af);
    ldb(&Bs[0][0], brow, co, b0);
    stA(gA, &As[1][0], wv, 1, t1);  // Am1(T+1) -> buf1
    BARM();
    mmq(af, b0, acc, 0, 0);
    BARM();
    // ph2 (m0,n1)
    ldb(&Bs[0][0], brow + 32, co, b1);
    stB(gB, &Bs[1][0], wv, 1, t1);  // Bn1(T+1) -> buf1
    BARM();
    mmq(af, b1, acc, 0, 1);
    BARM();
    // ph3 (m1,n0)
    lda(&As[0][0], arow + 64, co, af);
    stA(gA, &As[0][0], wv, 0, t2);  // Am0(T+2) -> buf0
    BARM();
    mmq(af, b0, acc, 1, 0);
    BARM();
    // ph4 (m1,n1)
    stB(gB, &Bs[0][0], wv, 0, t2);  // Bn0(T+2) -> buf0
    BARM();
    mmq(af, b1, acc, 1, 1);
    WVM(4);  // tile T+1 fully landed (outstanding = ph3+ph4 units)
    BARM();

    // ================= tile 2i+1 from buf1 =================
    // ph5 (m0,n0)
    lda(&As[1][0], arow, co, af);
    ldb(&Bs[1][0], brow, co, b0);
    stA(gA, &As[0][0], wv, 1, t2);  // Am1(T+2) -> buf0
    BARM();
    mmq(af, b0, acc, 0, 0);
    BARM();
    // ph6 (m0,n1)
    ldb(&Bs[1][0], brow + 32, co, b1);
    stB(gB, &Bs[0][0], wv, 1, t2);  // Bn1(T+2) -> buf0
    BARM();
    mmq(af, b1, acc, 0, 1);
    BARM();
    // ph7 (m1,n0)
    lda(&As[1][0], arow + 64, co, af);
    stA(gA, &As[1][0], wv, 0, t3);  // Am0(T+3) -> buf1
    BARM();
    mmq(af, b0, acc, 1, 0);
    BARM();
    // ph8 (m1,n1)
    stB(gB, &Bs[1][0], wv, 0, t3);  // Bn0(T+3) -> buf1
    BARM();
    mmq(af, b1, acc, 1, 1);
    WVM(4);  // tile T+2 fully landed (outstanding = ph7+ph8 units)
    BARM();
  }
  WVM(0);  // drain tail re-stages before LDS dealloc / epilogue

  // Epilogue: C layout col=lane&15, row=lq*4+r. Physical col n: even=re,
  // odd=im of h=n>>1; col parity == lane parity -> shfl_xor(1) pairs them.
  const int col = lane & 15;
  const int row0 = lq * 4;
  const int parity = lane & 1;
#pragma unroll
  for (int nq = 0; nq < 4; ++nq) {
    const int n = nBase + waveN * 64 + nq * 16 + col;
    const float bet = beta[n >> 1];
#pragma unroll
    for (int mq = 0; mq < 8; ++mq) {
      const int mrow = mBase + waveM * 128 + mq * 16 + row0;
#pragma unroll
      for (int r = 0; r < 4; ++r) {
        float a = acc[mq][nq][r];
        float o = __shfl_xor(a, 1);
        float re = parity ? o : a;
        float im = parity ? a : o;
        float mag2 = re * re + im * im;
        float val;
        if (mag2 > 0.f) {
          float rs = __frsqrt_rn(mag2);  // 1/mag
          float s = mag2 * rs + bet;     // mag + beta
          val = (s > 0.f) ? (parity ? im : re) * (s * rs) : 0.f;
        } else {
          val = (bet > 0.f && parity == 0) ? bet : 0.f;  // angle(0)==0
        }
        out[(size_t)(mrow + r) * 1024 + n] = val;
      }
    }
  }
}

// ---------------------------------------------------------------------------
extern "C" void kernel_launch(void* const* d_in, const int* in_sizes, int n_in,
                              void* d_out, int out_size, void* d_ws,
                              size_t ws_size, hipStream_t stream) {
  const float* x = (const float*)d_in[0];
  const float* hxre = (const float*)d_in[1];
  const float* hxim = (const float*)d_in[2];
  const float* ang = (const float*)d_in[3];
  const float* rre = (const float*)d_in[4];
  const float* rim = (const float*)d_in[5];
  const float* wre = (const float*)d_in[6];
  const float* wim = (const float*)d_in[7];
  const float* beta = (const float*)d_in[8];
  const int* perm = (const int*)d_in[9];

  char* ws = (char*)d_ws;
  bf16* Bm = (bf16*)ws;                                 // 1024x1280 bf16, 2.5 MiB
  bf16* Apack = (bf16*)(ws + (size_t)1024 * KTOT * 2);  // 16384x1280 bf16, 40 MiB

  prep<<<512 + (NB * 160) / 256, 256, 0, stream>>>(ang, rre, rim, wre, wim,
                                                   perm, hxre, hxim, x, Bm,
                                                   Apack);
  gemm_fused<<<256, 512, 0, stream>>>(Apack, Bm, beta, (float*)d_out);
}